// Round 3
// baseline (397.253 us; speedup 1.0000x reference)
//
#include <hip/hip_runtime.h>
#include <hip/hip_bf16.h>
#include <hip/hip_cooperative_groups.h>
#include <stdint.h>

#define BATCH 2
#define TT 2048
#define CC 1024
#define NH 16
#define HD 64
#define PST 72

namespace cg = cooperative_groups;

typedef __attribute__((ext_vector_type(8))) short short8;
typedef __attribute__((ext_vector_type(4))) float f32x4;
typedef __attribute__((ext_vector_type(2))) unsigned uint2v;

#define MFMA16 __builtin_amdgcn_mfma_f32_16x16x32_bf16
#define LOG2E 1.4426950408889634f

#if defined(__has_builtin)
#if __has_builtin(__builtin_amdgcn_exp2f)
#define EXP2(x) __builtin_amdgcn_exp2f(x)
#else
#define EXP2(x) __expf((x) * 0.6931471805599453f)
#endif
#else
#define EXP2(x) __expf((x) * 0.6931471805599453f)
#endif

__device__ __forceinline__ short f2bf(float f) {
  union { float f; unsigned u; } x;
  x.f = f;
  unsigned r = x.u + 0x7FFFu + ((x.u >> 16) & 1u);
  return (short)(r >> 16);
}

// ---------------------------------------------------------------------------
// Phase helpers. All share one 46080B LDS arena passed as SMEM; each unit
// begins with __syncthreads() to guard arena reuse across units/phases.
// ---------------------------------------------------------------------------

__device__ __forceinline__ void xcast_unit(const float* __restrict__ x,
                                           short* __restrict__ xb, int u,
                                           int tid) {
  const int i = (u * 256 + tid) * 8;
  const float4 a = *reinterpret_cast<const float4*>(&x[i]);
  const float4 b = *reinterpret_cast<const float4*>(&x[i + 4]);
  short8 o;
  o[0] = f2bf(a.x); o[1] = f2bf(a.y); o[2] = f2bf(a.z); o[3] = f2bf(a.w);
  o[4] = f2bf(b.x); o[5] = f2bf(b.y); o[6] = f2bf(b.z); o[7] = f2bf(b.w);
  *reinterpret_cast<short8*>(&xb[i]) = o;
}

__device__ __forceinline__ void transpose_cast_tile(
    const float* __restrict__ W, short* __restrict__ Wt, int K, int N,
    int n0, int k0, int tid, char* SMEM) {
  float (*Ls)[68] = (float (*)[68])SMEM;  // 64x68 f32 = 17408B
  __syncthreads();
  {
    const int r = tid >> 4, c4 = (tid & 15) * 4;
#pragma unroll
    for (int p = 0; p < 4; ++p) {
      const float4 v = *reinterpret_cast<const float4*>(
          &W[(size_t)(k0 + r + p * 16) * N + n0 + c4]);
      *reinterpret_cast<float4*>(&Ls[r + p * 16][c4]) = v;
    }
  }
  __syncthreads();
  {
    const int n = tid >> 2;
    const int kk0 = (tid & 3) * 16;
#pragma unroll
    for (int half = 0; half < 2; ++half) {
      short8 o;
#pragma unroll
      for (int t = 0; t < 8; ++t) o[t] = f2bf(Ls[kk0 + half * 8 + t][n]);
      *reinterpret_cast<short8*>(&Wt[(size_t)(n0 + n) * K + k0 + kk0 + half * 8]) = o;
    }
  }
}

__device__ __forceinline__ void tv_unit(const short* __restrict__ qkv,
                                        short* __restrict__ vT, int u, int tid,
                                        char* SMEM) {
  short (*Ls)[72] = (short (*)[72])SMEM;  // 64x72 bf16 = 9216B
  const int s0 = (u & 31) * 64;
  const int bh = u >> 5, b = bh >> 4, h = bh & 15;
  const int r = tid >> 3, c = (tid & 7) * 8;
  __syncthreads();
#pragma unroll
  for (int p = 0; p < 2; ++p) {
    *reinterpret_cast<short8*>(&Ls[r + p * 32][c]) =
        *reinterpret_cast<const short8*>(
            &qkv[(size_t)(b * TT + s0 + r + p * 32) * (3 * CC) + 2 * CC +
                 h * HD + c]);
  }
  __syncthreads();
  const int d = tid >> 2, ss = (tid & 3) * 16;
  short8 o0, o1;
#pragma unroll
  for (int t = 0; t < 8; ++t) { o0[t] = Ls[ss + t][d]; o1[t] = Ls[ss + 8 + t][d]; }
  short* dst = &vT[((size_t)(bh * HD + d)) * TT + s0 + ss];
  *reinterpret_cast<short8*>(dst) = o0;
  *reinterpret_cast<short8*>(dst + 8) = o1;
}

// GEMM tile: C[128,128] at (m0,n0) = A[M,K]*Bt[N,K]^T + bias. BK=64.
// Cols < QS get *(0.125*log2e) (q pre-scale + exp2-domain fold).
template <bool OUT_BF16>
__device__ void gemm_tile(const short* __restrict__ A,
                          const short* __restrict__ Bt,
                          const float* __restrict__ bias, void* __restrict__ C,
                          int N, int K, int QS, int m0, int n0, int tid,
                          char* SMEM) {
  short* As = (short*)SMEM;            // 8192 shorts
  short* Bs = (short*)(SMEM + 16384);  // 8192 shorts
  const int w = tid >> 6, lane = tid & 63;
  const int quad = lane >> 4, l15 = lane & 15;
  const int wm = (w >> 1) * 64, wn = (w & 1) * 64;

  f32x4 acc[4][4] = {};
  const int row16 = lane >> 2;
  const int c4 = (lane & 3) * 8;

  for (int k0 = 0; k0 < K; k0 += 64) {
    __syncthreads();
#pragma unroll
    for (int p = 0; p < 2; ++p) {
      const int rbase = __builtin_amdgcn_readfirstlane((w * 2 + p) * 16);
#pragma unroll
      for (int kh = 0; kh < 2; ++kh) {
        const short* ga = &A[(size_t)(m0 + rbase + row16) * K + k0 + kh * 32 + c4];
        const short* gb = &Bt[(size_t)(n0 + rbase + row16) * K + k0 + kh * 32 + c4];
        __builtin_amdgcn_global_load_lds(
            (const __attribute__((address_space(1))) void*)ga,
            (__attribute__((address_space(3))) void*)&As[kh * 4096 + rbase * 32],
            16, 0, 0);
        __builtin_amdgcn_global_load_lds(
            (const __attribute__((address_space(1))) void*)gb,
            (__attribute__((address_space(3))) void*)&Bs[kh * 4096 + rbase * 32],
            16, 0, 0);
      }
    }
    __syncthreads();

    short8 af[2][4], bfr[2][4];
#pragma unroll
    for (int kh = 0; kh < 2; ++kh) {
#pragma unroll
      for (int i = 0; i < 4; ++i)
        af[kh][i] = *reinterpret_cast<const short8*>(
            &As[kh * 4096 + (wm + i * 16 + l15) * 32 + quad * 8]);
#pragma unroll
      for (int j = 0; j < 4; ++j)
        bfr[kh][j] = *reinterpret_cast<const short8*>(
            &Bs[kh * 4096 + (wn + j * 16 + l15) * 32 + quad * 8]);
    }
#pragma unroll
    for (int kh = 0; kh < 2; ++kh)
#pragma unroll
      for (int i = 0; i < 4; ++i)
#pragma unroll
        for (int j = 0; j < 4; ++j)
          acc[i][j] = MFMA16(af[kh][i], bfr[kh][j], acc[i][j], 0, 0, 0);
  }

#pragma unroll
  for (int i = 0; i < 4; ++i) {
#pragma unroll
    for (int r = 0; r < 4; ++r) {
      const int row = m0 + wm + i * 16 + quad * 4 + r;
#pragma unroll
      for (int j = 0; j < 4; ++j) {
        const int col = n0 + wn + j * 16 + l15;
        float v = acc[i][j][r] + bias[col];
        if (col < QS) v *= 0.18033688011112042f;
        if (OUT_BF16)
          ((short*)C)[(size_t)row * N + col] = f2bf(v);
        else
          ((float*)C)[(size_t)row * N + col] = v;
      }
    }
  }
}

// MFMA flash attention unit (one (px,bh)): diagonal-paired q-tiles, 33 iters.
// Softmax in exp2 domain; P packed via __float22bfloat162_rn; mask hoisted.
__device__ void attn_unit(const short* __restrict__ qkv,
                          const short* __restrict__ vT,
                          const float* __restrict__ mask,
                          short* __restrict__ y, int px, int bh, int tid,
                          char* SMEM) {
  short* Ks = (short*)SMEM;             // [2][64*PST] = 18432B
  short* Vs = (short*)(SMEM + 18432);   // [2][64*PST]
  short* Ps = (short*)(SMEM + 36864);   // [64*PST]   = 9216B
  const int w = tid >> 6, lane = tid & 63;
  const int quad = lane >> 4, l15 = lane & 15;
  const int b = bh >> 4, h = bh & 15;
  const int qh = 31 - px;
  const int nth = qh + 1;
  const int ntot = nth + px + 1;  // == 33
  const int RS = 3 * CC;

  __syncthreads();  // guard LDS arena reuse

  int qt = qh;
  int qrow0 = qt * 64 + w * 16;

  short8 qf0, qf1;
  {
    const size_t qrow = (size_t)(b * TT + qrow0 + l15) * RS + h * HD + quad * 8;
    qf0 = *reinterpret_cast<const short8*>(&qkv[qrow]);
    qf1 = *reinterpret_cast<const short8*>(&qkv[qrow + 32]);
  }

  float l_run = 0.f;
  f32x4 o_acc[4] = {};

  const int sr = tid >> 3, sc = (tid & 7) * 8;
  const short* kbase = qkv + (size_t)(b * TT + sr) * RS + CC + h * HD + sc;
  const short* vbase = vT + (size_t)(bh * HD + sr) * TT + sc;
  const float* mptr = mask + b * TT + quad * 4;
  short* psrow = &Ps[(w * 16 + l15) * PST];
  const int kfo0 = quad * 8, kfo1 = 32 + quad * 8;

  short8 kpre0 = *reinterpret_cast<const short8*>(kbase);
  short8 kpre1 = *reinterpret_cast<const short8*>(kbase + (size_t)32 * RS);
  short8 vpre0 = *reinterpret_cast<const short8*>(vbase);
  short8 vpre1 = *reinterpret_cast<const short8*>(vbase + 32 * TT);

  for (int it = 0; it < ntot; ++it) {
    const int kt = (it < nth) ? it : it - nth;
    const int s0 = kt * 64;

    f32x4 mv[4];
#pragma unroll
    for (int j = 0; j < 4; ++j)
      mv[j] = *reinterpret_cast<const f32x4*>(&mptr[s0 + j * 16]);

    if (it == nth) {
#pragma unroll
      for (int r = 0; r < 4; ++r) {
        const float lr = __shfl(l_run, quad * 4 + r, 64);
        const float inv = 1.0f / lr;
        const size_t row = (size_t)(b * TT + qrow0 + quad * 4 + r);
#pragma unroll
        for (int t = 0; t < 4; ++t)
          y[row * CC + h * HD + t * 16 + l15] = f2bf(o_acc[t][r] * inv);
      }
      qt = px;
      qrow0 = qt * 64 + w * 16;
      const size_t qrow = (size_t)(b * TT + qrow0 + l15) * RS + h * HD + quad * 8;
      qf0 = *reinterpret_cast<const short8*>(&qkv[qrow]);
      qf1 = *reinterpret_cast<const short8*>(&qkv[qrow + 32]);
      l_run = 0.f;
#pragma unroll
      for (int t = 0; t < 4; ++t) o_acc[t] = f32x4{0.f, 0.f, 0.f, 0.f};
    }

    const int cur = it & 1;
    short* Kc = Ks + cur * (64 * PST);
    short* Vc = Vs + cur * (64 * PST);
    *reinterpret_cast<short8*>(&Kc[sr * PST + sc]) = kpre0;
    *reinterpret_cast<short8*>(&Kc[(sr + 32) * PST + sc]) = kpre1;
    *reinterpret_cast<short8*>(&Vc[sr * PST + sc]) = vpre0;
    *reinterpret_cast<short8*>(&Vc[(sr + 32) * PST + sc]) = vpre1;
    __syncthreads();

    if (it + 1 < ntot) {
      const int ktn = (it + 1 == nth) ? 0 : kt + 1;
      const short* kp = kbase + (size_t)ktn * 64 * RS;
      const short* vp = vbase + ktn * 64;
      kpre0 = *reinterpret_cast<const short8*>(kp);
      kpre1 = *reinterpret_cast<const short8*>(kp + (size_t)32 * RS);
      vpre0 = *reinterpret_cast<const short8*>(vp);
      vpre1 = *reinterpret_cast<const short8*>(vp + 32 * TT);
    }

    f32x4 sa[4] = {};
#pragma unroll
    for (int j = 0; j < 4; ++j) {
      const short8 kf0 = *reinterpret_cast<const short8*>(
          &Kc[(j * 16 + l15) * PST + kfo0]);
      const short8 kf1 = *reinterpret_cast<const short8*>(
          &Kc[(j * 16 + l15) * PST + kfo1]);
      sa[j] = MFMA16(kf0, qf0, sa[j], 0, 0, 0);
      sa[j] = MFMA16(kf1, qf1, sa[j], 0, 0, 0);
    }

    float rs = 0.f;
    const bool boundary = (kt == qt);
    const int qg = qrow0 + l15;
#pragma unroll
    for (int j = 0; j < 4; ++j) {
      float pv[4];
#pragma unroll
      for (int r = 0; r < 4; ++r) {
        float v = __builtin_fmaf(mv[j][r], LOG2E, sa[j][r]);
        if (boundary) {
          const int sg = s0 + j * 16 + quad * 4 + r;
          if (sg > qg) v = -10000.0f;
        }
        pv[r] = EXP2(v);
      }
      union { __hip_bfloat162 h2[2]; uint2v u; } pk;
      pk.h2[0] = __float22bfloat162_rn(make_float2(pv[0], pv[1]));
      pk.h2[1] = __float22bfloat162_rn(make_float2(pv[2], pv[3]));
      *reinterpret_cast<uint2v*>(&psrow[j * 16 + quad * 4]) = pk.u;
      rs += (pv[0] + pv[1]) + (pv[2] + pv[3]);
    }
    rs += __shfl_xor(rs, 16, 64);
    rs += __shfl_xor(rs, 32, 64);
    l_run += rs;

    const short8 pf0 = *reinterpret_cast<const short8*>(&psrow[kfo0]);
    const short8 pf1 = *reinterpret_cast<const short8*>(&psrow[kfo1]);
#pragma unroll
    for (int t = 0; t < 4; ++t) {
      const short8 vf0 = *reinterpret_cast<const short8*>(
          &Vc[(t * 16 + l15) * PST + kfo0]);
      const short8 vf1 = *reinterpret_cast<const short8*>(
          &Vc[(t * 16 + l15) * PST + kfo1]);
      o_acc[t] = MFMA16(pf0, vf0, o_acc[t], 0, 0, 0);
      o_acc[t] = MFMA16(pf1, vf1, o_acc[t], 0, 0, 0);
    }
  }

#pragma unroll
  for (int r = 0; r < 4; ++r) {
    const float lr = __shfl(l_run, quad * 4 + r, 64);
    const float inv = 1.0f / lr;
    const size_t row = (size_t)(b * TT + qrow0 + quad * 4 + r);
#pragma unroll
    for (int t = 0; t < 4; ++t)
      y[row * CC + h * HD + t * 16 + l15] = f2bf(o_acc[t][r] * inv);
  }
}

// ---------------------------------------------------------------------------
// Single cooperative kernel: prep -> QKV GEMM -> vT -> attention -> proj GEMM
// with grid.sync() between phases. Removes ~4 x ~13us inter-kernel overhead.
// Work partition per phase: balanced contiguous ranges [bid*W/nb,(bid+1)*W/nb)
// (robust to any block->CU assignment). LDS arena 46080B -> 3 blocks/CU.
// ---------------------------------------------------------------------------
__global__ __launch_bounds__(256) void fused_all(
    const float* __restrict__ x, short* __restrict__ xb,
    const float* __restrict__ W_attn, short* __restrict__ wat,
    const float* __restrict__ W_proj, short* __restrict__ wpt,
    const float* __restrict__ b_attn, short* __restrict__ qkvb,
    short* __restrict__ vTb, const float* __restrict__ mask,
    short* __restrict__ yb, const float* __restrict__ b_proj,
    float* __restrict__ out) {
  __shared__ __align__(16) char SMEM[46080];
  cg::grid_group grid = cg::this_grid();
  const int tid = threadIdx.x;
  const int bid = blockIdx.x;
  const int nb = gridDim.x;

  // phase 0: prep (2048 x-cast + 768 W_attn + 256 W_proj units)
  {
    const int u0 = (int)((long)bid * 3072 / nb);
    const int u1 = (int)((long)(bid + 1) * 3072 / nb);
    for (int u = u0; u < u1; ++u) {
      if (u < 2048) {
        xcast_unit(x, xb, u, tid);
      } else if (u < 2816) {
        const int b2 = u - 2048;
        transpose_cast_tile(W_attn, wat, CC, 3 * CC, (b2 % 48) * 64,
                            (b2 / 48) * 64, tid, SMEM);
      } else {
        const int b3 = u - 2816;
        transpose_cast_tile(W_proj, wpt, CC, CC, (b3 % 16) * 64,
                            (b3 / 16) * 64, tid, SMEM);
      }
    }
  }
  grid.sync();

  // phase 1: qkv = x @ W_attn + b_attn (q-third pre-scaled). 768 tiles.
  {
    const int t0 = (int)((long)bid * 768 / nb);
    const int t1 = (int)((long)(bid + 1) * 768 / nb);
    for (int t = t0; t < t1; ++t)
      gemm_tile<true>(xb, wat, b_attn, qkvb, 3 * CC, CC, CC,
                      (t / 24) * 128, (t % 24) * 128, tid, SMEM);
  }
  grid.sync();

  // phase 2: v -> vT. 1024 units.
  {
    const int u0 = (int)((long)bid * 1024 / nb);
    const int u1 = (int)((long)(bid + 1) * 1024 / nb);
    for (int u = u0; u < u1; ++u) tv_unit(qkvb, vTb, u, tid, SMEM);
  }
  grid.sync();

  // phase 3: attention. 512 units.
  {
    const int u0 = (int)((long)bid * 512 / nb);
    const int u1 = (int)((long)(bid + 1) * 512 / nb);
    for (int u = u0; u < u1; ++u)
      attn_unit(qkvb, vTb, mask, yb, u & 15, u >> 4, tid, SMEM);
  }
  grid.sync();

  // phase 4: out = y @ W_proj + b_proj (fp32 out). 256 tiles.
  {
    const int t0 = (int)((long)bid * 256 / nb);
    const int t1 = (int)((long)(bid + 1) * 256 / nb);
    for (int t = t0; t < t1; ++t)
      gemm_tile<false>(yb, wpt, b_proj, out, CC, CC, 0,
                       (t / 8) * 128, (t % 8) * 128, tid, SMEM);
  }
}

extern "C" void kernel_launch(void* const* d_in, const int* in_sizes, int n_in,
                              void* d_out, int out_size, void* d_ws,
                              size_t ws_size, hipStream_t stream) {
  const float* x = (const float*)d_in[0];
  const float* attn_mask = (const float*)d_in[1];
  const float* W_attn = (const float*)d_in[2];
  const float* b_attn = (const float*)d_in[3];
  const float* W_proj = (const float*)d_in[4];
  const float* b_proj = (const float*)d_in[5];
  float* out = (float*)d_out;

  const int M = BATCH * TT;  // 4096

  short* xb = (short*)d_ws;                       // [4096,1024]
  short* wat = xb + (size_t)M * CC;               // [3072,1024]
  short* wpt = wat + (size_t)(3 * CC) * CC;       // [1024,1024]
  short* qkvb = wpt + (size_t)CC * CC;            // [4096,3072]
  short* yb = qkvb + (size_t)M * 3 * CC;          // [4096,1024]
  short* vTb = yb + (size_t)M * CC;               // [2*16*64, 2048]

  // Cooperative grid: min(resident capacity, 768). Pure host query (no stream
  // ops) -> graph-capture safe; computed once.
  static int coop_grid = 0;
  if (coop_grid == 0) {
    int maxb = 0;
    if (hipOccupancyMaxActiveBlocksPerMultiprocessor(
            &maxb, (const void*)fused_all, 256, 0) != hipSuccess ||
        maxb < 1)
      maxb = 1;
    long nb = (long)maxb * 256;  // 256 CUs on MI355X
    if (nb > 768) nb = 768;
    coop_grid = (int)nb;
  }

  void* args[13] = {
      (void*)&x,     (void*)&xb,     (void*)&W_attn, (void*)&wat,
      (void*)&W_proj,(void*)&wpt,    (void*)&b_attn, (void*)&qkvb,
      (void*)&vTb,   (void*)&attn_mask, (void*)&yb,  (void*)&b_proj,
      (void*)&out};
  hipLaunchCooperativeKernel((const void*)fused_all, dim3(coop_grid),
                             dim3(256), args, 0, stream);
}

// Round 4
// 200.055 us; speedup vs baseline: 1.9857x; 1.9857x over previous
//
#include <hip/hip_runtime.h>
#include <hip/hip_bf16.h>
#include <stdint.h>

#define BATCH 2
#define TT 2048
#define CC 1024
#define NH 16
#define HD 64

typedef __attribute__((ext_vector_type(8))) short short8;
typedef __attribute__((ext_vector_type(4))) short sh4;
typedef __attribute__((ext_vector_type(4))) float f32x4;
typedef __attribute__((ext_vector_type(2))) unsigned uint2v;

#define MFMA16 __builtin_amdgcn_mfma_f32_16x16x32_bf16
#define LOG2E 1.4426950408889634f

#if defined(__has_builtin)
#if __has_builtin(__builtin_amdgcn_exp2f)
#define EXP2(x) __builtin_amdgcn_exp2f(x)
#else
#define EXP2(x) __expf((x) * 0.6931471805599453f)
#endif
#else
#define EXP2(x) __expf((x) * 0.6931471805599453f)
#endif

__device__ __forceinline__ short f2bf(float f) {
  union { float f; unsigned u; } x;
  x.f = f;
  unsigned r = x.u + 0x7FFFu + ((x.u >> 16) & 1u);
  return (short)(r >> 16);
}

// ---------------------------------------------------------------------------
// Fused prep: blocks [0,2048) cast x fp32->bf16; [2048,2816) transpose W_attn;
// [2816,3072) transpose W_proj. 256 threads.
// ---------------------------------------------------------------------------
__device__ __forceinline__ void transpose_cast_tile(
    const float* __restrict__ W, short* __restrict__ Wt, int K, int N,
    int n0, int k0, int tid) {
  __shared__ __align__(16) float Ls[64][68];
  {
    const int r = tid >> 4, c4 = (tid & 15) * 4;
#pragma unroll
    for (int p = 0; p < 4; ++p) {
      const float4 v = *reinterpret_cast<const float4*>(
          &W[(size_t)(k0 + r + p * 16) * N + n0 + c4]);
      *reinterpret_cast<float4*>(&Ls[r + p * 16][c4]) = v;
    }
  }
  __syncthreads();
  {
    const int n = tid >> 2;
    const int kk0 = (tid & 3) * 16;
#pragma unroll
    for (int half = 0; half < 2; ++half) {
      short8 o;
#pragma unroll
      for (int t = 0; t < 8; ++t) o[t] = f2bf(Ls[kk0 + half * 8 + t][n]);
      *reinterpret_cast<short8*>(&Wt[(size_t)(n0 + n) * K + k0 + kk0 + half * 8]) = o;
    }
  }
}

__global__ __launch_bounds__(256) void prep_fused(
    const float* __restrict__ x, short* __restrict__ xb,
    const float* __restrict__ W_attn, short* __restrict__ wat,
    const float* __restrict__ W_proj, short* __restrict__ wpt) {
  const int blk = blockIdx.x;
  const int tid = threadIdx.x;
  if (blk < 2048) {
    const int i = (blk * 256 + tid) * 8;
    const float4 a = *reinterpret_cast<const float4*>(&x[i]);
    const float4 b = *reinterpret_cast<const float4*>(&x[i + 4]);
    short8 o;
    o[0] = f2bf(a.x); o[1] = f2bf(a.y); o[2] = f2bf(a.z); o[3] = f2bf(a.w);
    o[4] = f2bf(b.x); o[5] = f2bf(b.y); o[6] = f2bf(b.z); o[7] = f2bf(b.w);
    *reinterpret_cast<short8*>(&xb[i]) = o;
  } else if (blk < 2816) {
    const int b2 = blk - 2048;
    transpose_cast_tile(W_attn, wat, CC, 3 * CC, (b2 % 48) * 64,
                        (b2 / 48) * 64, tid);
  } else {
    const int b3 = blk - 2816;
    transpose_cast_tile(W_proj, wpt, CC, CC, (b3 % 16) * 64, (b3 / 16) * 64,
                        tid);
  }
}

// ---------------------------------------------------------------------------
// GEMM: C[M,N] = A[M,K] * Bt[N,K]^T + bias, BK=64, LDS [kh][128][32].
// Cols < QS get *(0.125*log2e) (q pre-scale + exp2-domain fold). 256 thr.
// When vT != nullptr and the tile lies in the V third (n0 >= 2*CC), the tile
// is written TRANSPOSED to vT[bh][d][s] (via LDS re-transpose) instead of C
// -> the separate transpose_v kernel and its HBM round-trip are eliminated.
// ---------------------------------------------------------------------------
template <bool OUT_BF16>
__global__ __launch_bounds__(256) void gemm_bt_mfma(
    const short* __restrict__ A, const short* __restrict__ Bt,
    const float* __restrict__ bias, void* __restrict__ C,
    short* __restrict__ vT, int M, int N, int K, int QS) {
  __shared__ __align__(16) short As[2 * 128 * 32];
  __shared__ __align__(16) short Bs[2 * 128 * 32];
  const int tid = threadIdx.x;
  const int w = tid >> 6, lane = tid & 63;
  const int quad = lane >> 4, l15 = lane & 15;
  const int m0 = blockIdx.y * 128, n0 = blockIdx.x * 128;
  const int wm = (w >> 1) * 64, wn = (w & 1) * 64;

  f32x4 acc[4][4] = {};
  const int row16 = lane >> 2;
  const int c4 = (lane & 3) * 8;

  for (int k0 = 0; k0 < K; k0 += 64) {
    __syncthreads();
#pragma unroll
    for (int p = 0; p < 2; ++p) {
      const int rbase = __builtin_amdgcn_readfirstlane((w * 2 + p) * 16);
#pragma unroll
      for (int kh = 0; kh < 2; ++kh) {
        const short* ga = &A[(size_t)(m0 + rbase + row16) * K + k0 + kh * 32 + c4];
        const short* gb = &Bt[(size_t)(n0 + rbase + row16) * K + k0 + kh * 32 + c4];
        __builtin_amdgcn_global_load_lds(
            (const __attribute__((address_space(1))) void*)ga,
            (__attribute__((address_space(3))) void*)&As[kh * 4096 + rbase * 32],
            16, 0, 0);
        __builtin_amdgcn_global_load_lds(
            (const __attribute__((address_space(1))) void*)gb,
            (__attribute__((address_space(3))) void*)&Bs[kh * 4096 + rbase * 32],
            16, 0, 0);
      }
    }
    __syncthreads();

    short8 af[2][4], bfr[2][4];
#pragma unroll
    for (int kh = 0; kh < 2; ++kh) {
#pragma unroll
      for (int i = 0; i < 4; ++i)
        af[kh][i] = *reinterpret_cast<const short8*>(
            &As[kh * 4096 + (wm + i * 16 + l15) * 32 + quad * 8]);
#pragma unroll
      for (int j = 0; j < 4; ++j)
        bfr[kh][j] = *reinterpret_cast<const short8*>(
            &Bs[kh * 4096 + (wn + j * 16 + l15) * 32 + quad * 8]);
    }
#pragma unroll
    for (int kh = 0; kh < 2; ++kh)
#pragma unroll
      for (int i = 0; i < 4; ++i)
#pragma unroll
        for (int j = 0; j < 4; ++j)
          acc[i][j] = MFMA16(af[kh][i], bfr[kh][j], acc[i][j], 0, 0, 0);
  }

  if (OUT_BF16 && vT != nullptr && n0 >= 2 * CC) {
    // V-tile: bias-add then write transposed to vT[(b*16+h)*64+d][s].
    // Re-transpose through the As/Bs arena as Ls[64][136] (272B row = 17*16B,
    // so 16B vector ops stay aligned), one 64-d half at a time.
    const int n0v = n0 - 2 * CC;
    const int b = m0 >> 11;             // 2048 rows per batch; m0 128-aligned
    const int s_batch = m0 & (TT - 1);
    short* Ls = As;                     // 64*136*2 = 17408B <= 32KB arena
    __syncthreads();                    // all fragment reads of As/Bs done
#pragma unroll
    for (int half = 0; half < 2; ++half) {
      if ((w & 1) == half) {            // waves owning this 64-col half
#pragma unroll
        for (int i = 0; i < 4; ++i) {
#pragma unroll
          for (int j = 0; j < 4; ++j) {
            const int dl = (wn + j * 16 + l15) & 63;
            const int sl = wm + i * 16 + quad * 4;
            sh4 pw;
#pragma unroll
            for (int r = 0; r < 4; ++r)
              pw[r] = f2bf(acc[i][j][r] + bias[n0 + wn + j * 16 + l15]);
            *reinterpret_cast<sh4*>(&Ls[dl * 136 + sl]) = pw;
          }
        }
      }
      __syncthreads();
      {
        // 64 rows x 128 shorts: 4 threads/row, 64B (4x short8) each
        const int row = tid & 63, seg = tid >> 6;
        const short8* src =
            reinterpret_cast<const short8*>(&Ls[row * 136 + seg * 32]);
        const int bh = b * 16 + (n0v >> 6) + half;
        short8* dst = reinterpret_cast<short8*>(
            &vT[((size_t)(bh * HD + row)) * TT + s_batch + seg * 32]);
#pragma unroll
        for (int t = 0; t < 4; ++t) dst[t] = src[t];
      }
      __syncthreads();
    }
    return;
  }

#pragma unroll
  for (int i = 0; i < 4; ++i) {
#pragma unroll
    for (int r = 0; r < 4; ++r) {
      const int row = m0 + wm + i * 16 + quad * 4 + r;
#pragma unroll
      for (int j = 0; j < 4; ++j) {
        const int col = n0 + wn + j * 16 + l15;
        float v = acc[i][j][r] + bias[col];
        // 0.125 * log2(e): fold attn scale AND exp->exp2 domain change into q
        if (col < QS) v *= 0.18033688011112042f;
        if (OUT_BF16)
          ((short*)C)[(size_t)row * N + col] = f2bf(v);
        else
          ((float*)C)[(size_t)row * N + col] = v;
      }
    }
  }
}

// ---------------------------------------------------------------------------
// MFMA flash attention v8: 256 thr = 4 waves, 64-row q-tiles diagonal-paired
// (uniform 33 s-tile iters), grid 512 = 2 blocks/CU.
// Softmax in exp2 domain (q pre-scaled by 0.125*log2e; mask fused via fma
// with log2e). P packed via __float22bfloat162_rn. Mask loads hoisted.
// Grid: (16, B*NH).
// ---------------------------------------------------------------------------
#define PST 72
__global__ __launch_bounds__(256) void attn_mfma8(
    const short* __restrict__ qkv, const short* __restrict__ vT,
    const float* __restrict__ mask, short* __restrict__ y) {
  __shared__ __align__(16) short Ks[2][64 * PST];
  __shared__ __align__(16) short Vs[2][64 * PST];  // V^T tile [d][s]
  __shared__ __align__(16) short Ps[64 * PST];     // P [q_local][s]
  const int tid = threadIdx.x;
  const int w = tid >> 6, lane = tid & 63;
  const int quad = lane >> 4, l15 = lane & 15;
  const int bh = blockIdx.y, b = bh >> 4, h = bh & 15;
  const int px = blockIdx.x;          // 0..15
  const int qh = 31 - px;             // heavy q-tile (64 rows)
  const int nth = qh + 1;
  const int ntot = nth + px + 1;      // == 33, uniform
  const int RS = 3 * CC;

  int qt = qh;                        // current q-tile
  int qrow0 = qt * 64 + w * 16;

  short8 qf0, qf1;
  {
    const size_t qrow = (size_t)(b * TT + qrow0 + l15) * RS + h * HD + quad * 8;
    qf0 = *reinterpret_cast<const short8*>(&qkv[qrow]);
    qf1 = *reinterpret_cast<const short8*>(&qkv[qrow + 32]);
  }

  float l_run = 0.f;
  f32x4 o_acc[4] = {};

  const int sr = tid >> 3, sc = (tid & 7) * 8;
  const short* kbase = qkv + (size_t)(b * TT + sr) * RS + CC + h * HD + sc;
  const short* vbase = vT + (size_t)(bh * HD + sr) * TT + sc;
  const float* mptr = mask + b * TT + quad * 4;
  short* psrow = &Ps[(w * 16 + l15) * PST];
  const int kfo0 = quad * 8, kfo1 = 32 + quad * 8;

  short8 kpre0 = *reinterpret_cast<const short8*>(kbase);
  short8 kpre1 = *reinterpret_cast<const short8*>(kbase + (size_t)32 * RS);
  short8 vpre0 = *reinterpret_cast<const short8*>(vbase);
  short8 vpre1 = *reinterpret_cast<const short8*>(vbase + 32 * TT);

  for (int it = 0; it < ntot; ++it) {
    const int kt = (it < nth) ? it : it - nth;
    const int s0 = kt * 64;

    f32x4 mv[4];
#pragma unroll
    for (int j = 0; j < 4; ++j)
      mv[j] = *reinterpret_cast<const f32x4*>(&mptr[s0 + j * 16]);

    if (it == nth) {
#pragma unroll
      for (int r = 0; r < 4; ++r) {
        const float lr = __shfl(l_run, quad * 4 + r, 64);
        const float inv = 1.0f / lr;
        const size_t row = (size_t)(b * TT + qrow0 + quad * 4 + r);
#pragma unroll
        for (int t = 0; t < 4; ++t)
          y[row * CC + h * HD + t * 16 + l15] = f2bf(o_acc[t][r] * inv);
      }
      qt = px;
      qrow0 = qt * 64 + w * 16;
      const size_t qrow = (size_t)(b * TT + qrow0 + l15) * RS + h * HD + quad * 8;
      qf0 = *reinterpret_cast<const short8*>(&qkv[qrow]);
      qf1 = *reinterpret_cast<const short8*>(&qkv[qrow + 32]);
      l_run = 0.f;
#pragma unroll
      for (int t = 0; t < 4; ++t) o_acc[t] = f32x4{0.f, 0.f, 0.f, 0.f};
    }

    const int cur = it & 1;
    *reinterpret_cast<short8*>(&Ks[cur][sr * PST + sc]) = kpre0;
    *reinterpret_cast<short8*>(&Ks[cur][(sr + 32) * PST + sc]) = kpre1;
    *reinterpret_cast<short8*>(&Vs[cur][sr * PST + sc]) = vpre0;
    *reinterpret_cast<short8*>(&Vs[cur][(sr + 32) * PST + sc]) = vpre1;
    __syncthreads();

    if (it + 1 < ntot) {
      const int ktn = (it + 1 == nth) ? 0 : kt + 1;
      const short* kp = kbase + (size_t)ktn * 64 * RS;
      const short* vp = vbase + ktn * 64;
      kpre0 = *reinterpret_cast<const short8*>(kp);
      kpre1 = *reinterpret_cast<const short8*>(kp + (size_t)32 * RS);
      vpre0 = *reinterpret_cast<const short8*>(vp);
      vpre1 = *reinterpret_cast<const short8*>(vp + 32 * TT);
    }

    f32x4 sa[4] = {};
#pragma unroll
    for (int j = 0; j < 4; ++j) {
      const short8 kf0 = *reinterpret_cast<const short8*>(
          &Ks[cur][(j * 16 + l15) * PST + kfo0]);
      const short8 kf1 = *reinterpret_cast<const short8*>(
          &Ks[cur][(j * 16 + l15) * PST + kfo1]);
      sa[j] = MFMA16(kf0, qf0, sa[j], 0, 0, 0);
      sa[j] = MFMA16(kf1, qf1, sa[j], 0, 0, 0);
    }

    float rs = 0.f;
    const bool boundary = (kt == qt);
    const int qg = qrow0 + l15;
#pragma unroll
    for (int j = 0; j < 4; ++j) {
      float pv[4];
#pragma unroll
      for (int r = 0; r < 4; ++r) {
        float v = __builtin_fmaf(mv[j][r], LOG2E, sa[j][r]);
        if (boundary) {
          const int sg = s0 + j * 16 + quad * 4 + r;
          if (sg > qg) v = -10000.0f;
        }
        pv[r] = EXP2(v);
      }
      union { __hip_bfloat162 h2[2]; uint2v u; } pk;
      pk.h2[0] = __float22bfloat162_rn(make_float2(pv[0], pv[1]));
      pk.h2[1] = __float22bfloat162_rn(make_float2(pv[2], pv[3]));
      *reinterpret_cast<uint2v*>(&psrow[j * 16 + quad * 4]) = pk.u;
      rs += (pv[0] + pv[1]) + (pv[2] + pv[3]);
    }
    rs += __shfl_xor(rs, 16, 64);
    rs += __shfl_xor(rs, 32, 64);
    l_run += rs;

    const short8 pf0 = *reinterpret_cast<const short8*>(&psrow[kfo0]);
    const short8 pf1 = *reinterpret_cast<const short8*>(&psrow[kfo1]);
#pragma unroll
    for (int t = 0; t < 4; ++t) {
      const short8 vf0 = *reinterpret_cast<const short8*>(
          &Vs[cur][(t * 16 + l15) * PST + kfo0]);
      const short8 vf1 = *reinterpret_cast<const short8*>(
          &Vs[cur][(t * 16 + l15) * PST + kfo1]);
      o_acc[t] = MFMA16(pf0, vf0, o_acc[t], 0, 0, 0);
      o_acc[t] = MFMA16(pf1, vf1, o_acc[t], 0, 0, 0);
    }
  }

#pragma unroll
  for (int r = 0; r < 4; ++r) {
    const float lr = __shfl(l_run, quad * 4 + r, 64);
    const float inv = 1.0f / lr;
    const size_t row = (size_t)(b * TT + qrow0 + quad * 4 + r);
#pragma unroll
    for (int t = 0; t < 4; ++t)
      y[row * CC + h * HD + t * 16 + l15] = f2bf(o_acc[t][r] * inv);
  }
}

extern "C" void kernel_launch(void* const* d_in, const int* in_sizes, int n_in,
                              void* d_out, int out_size, void* d_ws,
                              size_t ws_size, hipStream_t stream) {
  const float* x = (const float*)d_in[0];
  const float* attn_mask = (const float*)d_in[1];
  const float* W_attn = (const float*)d_in[2];
  const float* b_attn = (const float*)d_in[3];
  const float* W_proj = (const float*)d_in[4];
  const float* b_proj = (const float*)d_in[5];
  float* out = (float*)d_out;

  const int M = BATCH * TT;  // 4096

  short* xb = (short*)d_ws;                       // [4096,1024]
  short* wat = xb + (size_t)M * CC;               // [3072,1024]
  short* wpt = wat + (size_t)(3 * CC) * CC;       // [1024,1024]
  short* qkvb = wpt + (size_t)CC * CC;            // [4096,3072] (v third unused)
  short* yb = qkvb + (size_t)M * 3 * CC;          // [4096,1024]
  short* vTb = yb + (size_t)M * CC;               // [2*16*64, 2048]

  prep_fused<<<3072, 256, 0, stream>>>(x, xb, W_attn, wat, W_proj, wpt);

  // qkv = x @ W_attn + b_attn; q-third scaled by 0.125*log2e (exp2 fold);
  // v-third written transposed straight into vTb (transpose_v eliminated).
  gemm_bt_mfma<true><<<dim3((3 * CC) / 128, M / 128), 256, 0, stream>>>(
      xb, wat, b_attn, qkvb, vTb, M, 3 * CC, CC, CC);

  attn_mfma8<<<dim3(16, BATCH * NH), 256, 0, stream>>>(
      qkvb, vTb, attn_mask, yb);

  gemm_bt_mfma<false><<<dim3(CC / 128, M / 128), 256, 0, stream>>>(
      yb, wpt, b_proj, out, nullptr, M, CC, CC, 0);
}

// Round 6
// 194.226 us; speedup vs baseline: 2.0453x; 1.0300x over previous
//
#include <hip/hip_runtime.h>
#include <hip/hip_bf16.h>
#include <stdint.h>

#define BATCH 2
#define TT 2048
#define CC 1024
#define NH 16
#define HD 64

typedef __attribute__((ext_vector_type(8))) short short8;
typedef __attribute__((ext_vector_type(4))) short sh4;
typedef __attribute__((ext_vector_type(4))) float f32x4;
typedef __attribute__((ext_vector_type(2))) unsigned uint2v;

#define MFMA16 __builtin_amdgcn_mfma_f32_16x16x32_bf16
#define LOG2E 1.4426950408889634f

#if defined(__has_builtin)
#if __has_builtin(__builtin_amdgcn_exp2f)
#define EXP2(x) __builtin_amdgcn_exp2f(x)
#else
#define EXP2(x) __expf((x) * 0.6931471805599453f)
#endif
#else
#define EXP2(x) __expf((x) * 0.6931471805599453f)
#endif

__device__ __forceinline__ short f2bf(float f) {
  union { float f; unsigned u; } x;
  x.f = f;
  unsigned r = x.u + 0x7FFFu + ((x.u >> 16) & 1u);
  return (short)(r >> 16);
}

// ---------------------------------------------------------------------------
// Fused prep: blocks [0,2048) cast x fp32->bf16; [2048,2816) transpose W_attn;
// [2816,3072) transpose W_proj. 256 threads.
// ---------------------------------------------------------------------------
__device__ __forceinline__ void transpose_cast_tile(
    const float* __restrict__ W, short* __restrict__ Wt, int K, int N,
    int n0, int k0, int tid) {
  __shared__ __align__(16) float Ls[64][68];
  {
    const int r = tid >> 4, c4 = (tid & 15) * 4;
#pragma unroll
    for (int p = 0; p < 4; ++p) {
      const float4 v = *reinterpret_cast<const float4*>(
          &W[(size_t)(k0 + r + p * 16) * N + n0 + c4]);
      *reinterpret_cast<float4*>(&Ls[r + p * 16][c4]) = v;
    }
  }
  __syncthreads();
  {
    const int n = tid >> 2;
    const int kk0 = (tid & 3) * 16;
#pragma unroll
    for (int half = 0; half < 2; ++half) {
      short8 o;
#pragma unroll
      for (int t = 0; t < 8; ++t) o[t] = f2bf(Ls[kk0 + half * 8 + t][n]);
      *reinterpret_cast<short8*>(&Wt[(size_t)(n0 + n) * K + k0 + kk0 + half * 8]) = o;
    }
  }
}

__global__ __launch_bounds__(256) void prep_fused(
    const float* __restrict__ x, short* __restrict__ xb,
    const float* __restrict__ W_attn, short* __restrict__ wat,
    const float* __restrict__ W_proj, short* __restrict__ wpt) {
  const int blk = blockIdx.x;
  const int tid = threadIdx.x;
  if (blk < 2048) {
    const int i = (blk * 256 + tid) * 8;
    const float4 a = *reinterpret_cast<const float4*>(&x[i]);
    const float4 b = *reinterpret_cast<const float4*>(&x[i + 4]);
    short8 o;
    o[0] = f2bf(a.x); o[1] = f2bf(a.y); o[2] = f2bf(a.z); o[3] = f2bf(a.w);
    o[4] = f2bf(b.x); o[5] = f2bf(b.y); o[6] = f2bf(b.z); o[7] = f2bf(b.w);
    *reinterpret_cast<short8*>(&xb[i]) = o;
  } else if (blk < 2816) {
    const int b2 = blk - 2048;
    transpose_cast_tile(W_attn, wat, CC, 3 * CC, (b2 % 48) * 64,
                        (b2 / 48) * 64, tid);
  } else {
    const int b3 = blk - 2816;
    transpose_cast_tile(W_proj, wpt, CC, CC, (b3 % 16) * 64, (b3 / 16) * 64,
                        tid);
  }
}

// ---------------------------------------------------------------------------
// GEMM 64x128 tile: C[64,128] at (m0,n0) = A[M,K]*Bt[N,K]^T + bias. BK=64.
// 4 waves; each wave owns all 64 M-rows x 32 N-cols (acc[4][2]). LDS 24KB ->
// 6 blocks/CU (QKV grid 1536) / 2 blocks/CU (proj grid 512) for latency
// hiding (round-4 profile: 1-3 blocks/CU, all pipes <30% busy).
// Cols < QS get *(0.125*log2e) (q pre-scale + exp2-domain fold).
// V third (n0 >= 2*CC, vT != nullptr): tile written TRANSPOSED to vT[bh][d][s]
// via LDS re-transpose (the separate transpose_v kernel stays eliminated).
// ---------------------------------------------------------------------------
template <bool OUT_BF16>
__device__ __forceinline__ void gemm_bt_body(
    const short* __restrict__ A, const short* __restrict__ Bt,
    const float* __restrict__ bias, void* __restrict__ C,
    short* __restrict__ vT, int M, int N, int K, int QS) {
  __shared__ __align__(16) short SM[12288];  // 24KB arena
  short* As = SM;            // [2][64][32]  = 4096 shorts
  short* Bs = SM + 4096;     // [2][128][32] = 8192 shorts
  const int tid = threadIdx.x;
  const int w = tid >> 6, lane = tid & 63;
  const int quad = lane >> 4, l15 = lane & 15;
  const int m0 = blockIdx.y * 64, n0 = blockIdx.x * 128;

  f32x4 acc[4][2] = {};
  const int row16 = lane >> 2;
  const int c4 = (lane & 3) * 8;

  for (int k0 = 0; k0 < K; k0 += 64) {
    __syncthreads();
    {
      const int rbaseA = __builtin_amdgcn_readfirstlane(w * 16);
#pragma unroll
      for (int kh = 0; kh < 2; ++kh) {
        const short* ga = &A[(size_t)(m0 + rbaseA + row16) * K + k0 + kh * 32 + c4];
        __builtin_amdgcn_global_load_lds(
            (const __attribute__((address_space(1))) void*)ga,
            (__attribute__((address_space(3))) void*)&As[kh * 2048 + rbaseA * 32],
            16, 0, 0);
      }
    }
#pragma unroll
    for (int p = 0; p < 2; ++p) {
      const int rbase = __builtin_amdgcn_readfirstlane((w * 2 + p) * 16);
#pragma unroll
      for (int kh = 0; kh < 2; ++kh) {
        const short* gb = &Bt[(size_t)(n0 + rbase + row16) * K + k0 + kh * 32 + c4];
        __builtin_amdgcn_global_load_lds(
            (const __attribute__((address_space(1))) void*)gb,
            (__attribute__((address_space(3))) void*)&Bs[kh * 4096 + rbase * 32],
            16, 0, 0);
      }
    }
    __syncthreads();

    short8 af[2][4], bfr[2][2];
#pragma unroll
    for (int kh = 0; kh < 2; ++kh) {
#pragma unroll
      for (int i = 0; i < 4; ++i)
        af[kh][i] = *reinterpret_cast<const short8*>(
            &As[kh * 2048 + (i * 16 + l15) * 32 + quad * 8]);
#pragma unroll
      for (int j = 0; j < 2; ++j)
        bfr[kh][j] = *reinterpret_cast<const short8*>(
            &Bs[kh * 4096 + (w * 32 + j * 16 + l15) * 32 + quad * 8]);
    }
#pragma unroll
    for (int kh = 0; kh < 2; ++kh)
#pragma unroll
      for (int i = 0; i < 4; ++i)
#pragma unroll
        for (int j = 0; j < 2; ++j)
          acc[i][j] = MFMA16(af[kh][i], bfr[kh][j], acc[i][j], 0, 0, 0);
  }

  if (OUT_BF16 && vT != nullptr && n0 >= 2 * CC) {
    // V-tile: 64 s-rows x 128 d-cols -> write transposed vT[bh][d][s].
    // Arena as Ls[128][88] (176B rows = 11*16B aligned). Waves own disjoint
    // d-ranges (dl = w*32+...), single pass.
    const int n0v = n0 - 2 * CC;
    const int b = m0 >> 11;
    const int s_batch = m0 & (TT - 1);
    short* Ls = SM;  // 128*88 = 11264 shorts <= 12288
    __syncthreads();  // all fragment reads of As/Bs done
#pragma unroll
    for (int i = 0; i < 4; ++i) {
#pragma unroll
      for (int j = 0; j < 2; ++j) {
        const int dl = w * 32 + j * 16 + l15;
        const int sl = i * 16 + quad * 4;
        const float bb = bias[n0 + dl];
        sh4 pw;
#pragma unroll
        for (int r = 0; r < 4; ++r) pw[r] = f2bf(acc[i][j][r] + bb);
        *reinterpret_cast<sh4*>(&Ls[dl * 88 + sl]) = pw;
      }
    }
    __syncthreads();
    {
      const int row = tid >> 1, seg = tid & 1;  // 128 d-rows, 2 x 64B segs
      const int bh = b * 16 + (n0v >> 6) + (row >> 6);
      const int d = row & 63;
      const short8* src = reinterpret_cast<const short8*>(&Ls[row * 88 + seg * 32]);
      short8* dst = reinterpret_cast<short8*>(
          &vT[((size_t)(bh * HD + d)) * TT + s_batch + seg * 32]);
#pragma unroll
      for (int t = 0; t < 4; ++t) dst[t] = src[t];
    }
    return;
  }

#pragma unroll
  for (int i = 0; i < 4; ++i) {
#pragma unroll
    for (int r = 0; r < 4; ++r) {
      const int row = m0 + i * 16 + quad * 4 + r;
#pragma unroll
      for (int j = 0; j < 2; ++j) {
        const int col = n0 + w * 32 + j * 16 + l15;
        float v = acc[i][j][r] + bias[col];
        // 0.125 * log2(e): fold attn scale AND exp->exp2 domain change into q
        if (col < QS) v *= 0.18033688011112042f;
        if (OUT_BF16)
          ((short*)C)[(size_t)row * N + col] = f2bf(v);
        else
          ((float*)C)[(size_t)row * N + col] = v;
      }
    }
  }
}

__global__ __launch_bounds__(256) void gemm_qkv(
    const short* __restrict__ A, const short* __restrict__ Bt,
    const float* __restrict__ bias, void* __restrict__ C,
    short* __restrict__ vT, int M, int N, int K, int QS) {
  gemm_bt_body<true>(A, Bt, bias, C, vT, M, N, K, QS);
}

__global__ __launch_bounds__(256) void gemm_proj(
    const short* __restrict__ A, const short* __restrict__ Bt,
    const float* __restrict__ bias, void* __restrict__ C, int M, int N,
    int K) {
  gemm_bt_body<false>(A, Bt, bias, C, nullptr, M, N, K, 0);
}

// ---------------------------------------------------------------------------
// MFMA flash attention v8: 256 thr = 4 waves, 64-row q-tiles diagonal-paired
// (uniform 33 s-tile iters), grid 512 = 2 blocks/CU.
// Softmax in exp2 domain (q pre-scaled by 0.125*log2e; mask fused via fma
// with log2e). P packed via __float22bfloat162_rn. Mask loads hoisted.
// Grid: (16, B*NH).
// ---------------------------------------------------------------------------
#define PST 72
__global__ __launch_bounds__(256) void attn_mfma8(
    const short* __restrict__ qkv, const short* __restrict__ vT,
    const float* __restrict__ mask, short* __restrict__ y) {
  __shared__ __align__(16) short Ks[2][64 * PST];
  __shared__ __align__(16) short Vs[2][64 * PST];  // V^T tile [d][s]
  __shared__ __align__(16) short Ps[64 * PST];     // P [q_local][s]
  const int tid = threadIdx.x;
  const int w = tid >> 6, lane = tid & 63;
  const int quad = lane >> 4, l15 = lane & 15;
  const int bh = blockIdx.y, b = bh >> 4, h = bh & 15;
  const int px = blockIdx.x;          // 0..15
  const int qh = 31 - px;             // heavy q-tile (64 rows)
  const int nth = qh + 1;
  const int ntot = nth + px + 1;      // == 33, uniform
  const int RS = 3 * CC;

  int qt = qh;                        // current q-tile
  int qrow0 = qt * 64 + w * 16;

  short8 qf0, qf1;
  {
    const size_t qrow = (size_t)(b * TT + qrow0 + l15) * RS + h * HD + quad * 8;
    qf0 = *reinterpret_cast<const short8*>(&qkv[qrow]);
    qf1 = *reinterpret_cast<const short8*>(&qkv[qrow + 32]);
  }

  float l_run = 0.f;
  f32x4 o_acc[4] = {};

  const int sr = tid >> 3, sc = (tid & 7) * 8;
  const short* kbase = qkv + (size_t)(b * TT + sr) * RS + CC + h * HD + sc;
  const short* vbase = vT + (size_t)(bh * HD + sr) * TT + sc;
  const float* mptr = mask + b * TT + quad * 4;
  short* psrow = &Ps[(w * 16 + l15) * PST];
  const int kfo0 = quad * 8, kfo1 = 32 + quad * 8;

  short8 kpre0 = *reinterpret_cast<const short8*>(kbase);
  short8 kpre1 = *reinterpret_cast<const short8*>(kbase + (size_t)32 * RS);
  short8 vpre0 = *reinterpret_cast<const short8*>(vbase);
  short8 vpre1 = *reinterpret_cast<const short8*>(vbase + 32 * TT);

  for (int it = 0; it < ntot; ++it) {
    const int kt = (it < nth) ? it : it - nth;
    const int s0 = kt * 64;

    f32x4 mv[4];
#pragma unroll
    for (int j = 0; j < 4; ++j)
      mv[j] = *reinterpret_cast<const f32x4*>(&mptr[s0 + j * 16]);

    if (it == nth) {
#pragma unroll
      for (int r = 0; r < 4; ++r) {
        const float lr = __shfl(l_run, quad * 4 + r, 64);
        const float inv = 1.0f / lr;
        const size_t row = (size_t)(b * TT + qrow0 + quad * 4 + r);
#pragma unroll
        for (int t = 0; t < 4; ++t)
          y[row * CC + h * HD + t * 16 + l15] = f2bf(o_acc[t][r] * inv);
      }
      qt = px;
      qrow0 = qt * 64 + w * 16;
      const size_t qrow = (size_t)(b * TT + qrow0 + l15) * RS + h * HD + quad * 8;
      qf0 = *reinterpret_cast<const short8*>(&qkv[qrow]);
      qf1 = *reinterpret_cast<const short8*>(&qkv[qrow + 32]);
      l_run = 0.f;
#pragma unroll
      for (int t = 0; t < 4; ++t) o_acc[t] = f32x4{0.f, 0.f, 0.f, 0.f};
    }

    const int cur = it & 1;
    *reinterpret_cast<short8*>(&Ks[cur][sr * PST + sc]) = kpre0;
    *reinterpret_cast<short8*>(&Ks[cur][(sr + 32) * PST + sc]) = kpre1;
    *reinterpret_cast<short8*>(&Vs[cur][sr * PST + sc]) = vpre0;
    *reinterpret_cast<short8*>(&Vs[cur][(sr + 32) * PST + sc]) = vpre1;
    __syncthreads();

    if (it + 1 < ntot) {
      const int ktn = (it + 1 == nth) ? 0 : kt + 1;
      const short* kp = kbase + (size_t)ktn * 64 * RS;
      const short* vp = vbase + ktn * 64;
      kpre0 = *reinterpret_cast<const short8*>(kp);
      kpre1 = *reinterpret_cast<const short8*>(kp + (size_t)32 * RS);
      vpre0 = *reinterpret_cast<const short8*>(vp);
      vpre1 = *reinterpret_cast<const short8*>(vp + 32 * TT);
    }

    f32x4 sa[4] = {};
#pragma unroll
    for (int j = 0; j < 4; ++j) {
      const short8 kf0 = *reinterpret_cast<const short8*>(
          &Ks[cur][(j * 16 + l15) * PST + kfo0]);
      const short8 kf1 = *reinterpret_cast<const short8*>(
          &Ks[cur][(j * 16 + l15) * PST + kfo1]);
      sa[j] = MFMA16(kf0, qf0, sa[j], 0, 0, 0);
      sa[j] = MFMA16(kf1, qf1, sa[j], 0, 0, 0);
    }

    float rs = 0.f;
    const bool boundary = (kt == qt);
    const int qg = qrow0 + l15;
#pragma unroll
    for (int j = 0; j < 4; ++j) {
      float pv[4];
#pragma unroll
      for (int r = 0; r < 4; ++r) {
        float v = __builtin_fmaf(mv[j][r], LOG2E, sa[j][r]);
        if (boundary) {
          const int sg = s0 + j * 16 + quad * 4 + r;
          if (sg > qg) v = -10000.0f;
        }
        pv[r] = EXP2(v);
      }
      union { __hip_bfloat162 h2[2]; uint2v u; } pk;
      pk.h2[0] = __float22bfloat162_rn(make_float2(pv[0], pv[1]));
      pk.h2[1] = __float22bfloat162_rn(make_float2(pv[2], pv[3]));
      *reinterpret_cast<uint2v*>(&psrow[j * 16 + quad * 4]) = pk.u;
      rs += (pv[0] + pv[1]) + (pv[2] + pv[3]);
    }
    rs += __shfl_xor(rs, 16, 64);
    rs += __shfl_xor(rs, 32, 64);
    l_run += rs;

    const short8 pf0 = *reinterpret_cast<const short8*>(&psrow[kfo0]);
    const short8 pf1 = *reinterpret_cast<const short8*>(&psrow[kfo1]);
#pragma unroll
    for (int t = 0; t < 4; ++t) {
      const short8 vf0 = *reinterpret_cast<const short8*>(
          &Vs[cur][(t * 16 + l15) * PST + kfo0]);
      const short8 vf1 = *reinterpret_cast<const short8*>(
          &Vs[cur][(t * 16 + l15) * PST + kfo1]);
      o_acc[t] = MFMA16(pf0, vf0, o_acc[t], 0, 0, 0);
      o_acc[t] = MFMA16(pf1, vf1, o_acc[t], 0, 0, 0);
    }
  }

#pragma unroll
  for (int r = 0; r < 4; ++r) {
    const float lr = __shfl(l_run, quad * 4 + r, 64);
    const float inv = 1.0f / lr;
    const size_t row = (size_t)(b * TT + qrow0 + quad * 4 + r);
#pragma unroll
    for (int t = 0; t < 4; ++t)
      y[row * CC + h * HD + t * 16 + l15] = f2bf(o_acc[t][r] * inv);
  }
}

extern "C" void kernel_launch(void* const* d_in, const int* in_sizes, int n_in,
                              void* d_out, int out_size, void* d_ws,
                              size_t ws_size, hipStream_t stream) {
  const float* x = (const float*)d_in[0];
  const float* attn_mask = (const float*)d_in[1];
  const float* W_attn = (const float*)d_in[2];
  const float* b_attn = (const float*)d_in[3];
  const float* W_proj = (const float*)d_in[4];
  const float* b_proj = (const float*)d_in[5];
  float* out = (float*)d_out;

  const int M = BATCH * TT;  // 4096

  short* xb = (short*)d_ws;                       // [4096,1024]
  short* wat = xb + (size_t)M * CC;               // [3072,1024]
  short* wpt = wat + (size_t)(3 * CC) * CC;       // [1024,1024]
  short* qkvb = wpt + (size_t)CC * CC;            // [4096,3072] (v third unused)
  short* yb = qkvb + (size_t)M * 3 * CC;          // [4096,1024]
  short* vTb = yb + (size_t)M * CC;               // [2*16*64, 2048]

  prep_fused<<<3072, 256, 0, stream>>>(x, xb, W_attn, wat, W_proj, wpt);

  // qkv = x @ W_attn + b_attn; q-third scaled by 0.125*log2e (exp2 fold);
  // v-third written transposed straight into vTb. 1536 blocks = 6/CU.
  gemm_qkv<<<dim3((3 * CC) / 128, M / 64), 256, 0, stream>>>(
      xb, wat, b_attn, qkvb, vTb, M, 3 * CC, CC, CC);

  attn_mfma8<<<dim3(16, BATCH * NH), 256, 0, stream>>>(
      qkvb, vTb, attn_mask, yb);

  // out = y @ W_proj + b_proj. 512 blocks = 2/CU (was 256 = 1/CU).
  gemm_proj<<<dim3(CC / 128, M / 64), 256, 0, stream>>>(
      yb, wpt, b_proj, out, M, CC, CC);
}